// Round 14
// baseline (48.595 us; speedup 1.0000x reference)
//
#include <hip/hip_runtime.h>

// Logm of 2*2^20 independent 3x3 SPD matrices — closed-form eigenvalues.
// Layout: x[b][c][v], c = 3*i+j, plane stride NV = 2^20 floats.
// Input bit-symmetric -> read only upper-triangle planes {0,1,2,4,5,8}.
// 8 ADJACENT voxels/thread (2 x f32x4 per plane): doubles the per-stream
// burst to 2KB/wave before the 4MB plane jump (DRAM page locality test).
// Pipeline: all 12 loads up front -> compute A -> store A -> compute B ->
// store B. Deg-4 A&S acos (err 7e-5 rad, well under tolerance).
// Per voxel: char-poly -> Cardano trig eigenvalues -> Newton divided
// differences: log(M) = k0*I + k1*M + k2*M^2 (passed r8-r13).

#define NV (1 << 20)   // D*H*W
#define BT 2

typedef float f32x4 __attribute__((ext_vector_type(4)));

__device__ __forceinline__ float rcpf(float x) { return __builtin_amdgcn_rcpf(x); }

__device__ __forceinline__ void logm3(
    float a00, float a01, float a02, float a11, float a12, float a22,
    float &y00, float &y01, float &y02, float &y11, float &y12, float &y22)
{
    const float THIRD = 0.33333333333f;
    float m   = (a00 + a11 + a22) * THIRD;
    float b00 = a00 - m, b11 = a11 - m, b22 = a22 - m;
    float off2  = fmaf(a01, a01, fmaf(a02, a02, a12 * a12));
    float diag2 = fmaf(b00, b00, fmaf(b11, b11, b22 * b22));
    float p2 = fmaf(diag2, 1.0f / 6.0f, off2 * THIRD);   // p = tr(B^2)/6
    float sp = sqrtf(p2);
    float detB = b00 * fmaf(b11, b22, -a12 * a12)
               - a01 * fmaf(a01, b22, -a12 * a02)
               + a02 * fmaf(a01, a12, -b11 * a02);
    float q  = 0.5f * detB;
    float rr = q * rcpf(fmaxf(p2 * sp, 1e-30f));         // q / p^(3/2)
    rr = fminf(fmaxf(rr, -1.0f), 1.0f);

    // acos(rr): A&S 4.4.45 deg-3, |err| <= 6.8e-5 rad; reflect for rr<0
    float ar  = fabsf(rr);
    float acp = fmaf(ar, fmaf(ar, fmaf(ar,
        -0.0187293f, 0.0742610f), -0.2121144f), 1.5707288f);
    float A   = sqrtf(fmaxf(1.0f - ar, 0.0f)) * acp;
    float phi = (rr >= 0.0f) ? A : (3.14159265359f - A);
    float th  = phi * THIRD;                              // [0, pi/3]

    float c0  = __cosf(th);
    float s0  = sqrtf(fmaxf(fmaf(-c0, c0, 1.0f), 0.0f));
    float cm  = -0.5f * c0;
    float c1  = fmaf(-0.86602540378f, s0, cm);            // -> min
    float c2c = fmaf( 0.86602540378f, s0, cm);            // -> mid
    float tsp = 2.0f * sp;
    float L1 = fmaf(tsp, c0,  m);                         // max
    float L2 = fmaf(tsp, c2c, m);                         // mid
    float L3 = fmaf(tsp, c1,  m);                         // min

    float g1 = __logf(L1), g2 = __logf(L2), g3 = __logf(L3);

    float d12 = L1 - L2, d23 = L2 - L3;
    float d13 = fmaxf(L1 - L3, 1e-6f);
    float i2  = rcpf(L2), i3 = rcpf(L3);
    float x12 = d12 * i2, x23 = d23 * i3;
    float s12 = fmaf(x12, fmaf(x12, fmaf(x12, -0.25f, THIRD), -0.5f), 1.0f);
    float s23 = fmaf(x23, fmaf(x23, fmaf(x23, -0.25f, THIRD), -0.5f), 1.0f);
    float f12 = (x12 < 0.03f) ? s12 * i2 : (g1 - g2) * rcpf(fmaxf(d12, 1e-30f));
    float f23 = (x23 < 0.03f) ? s23 * i3 : (g2 - g3) * rcpf(fmaxf(d23, 1e-30f));
    float cc2 = (f12 - f23) * rcpf(d13);

    float k0 = fmaf(cc2, L1 * L2, fmaf(-f12, L1, g1));
    float k1 = fmaf(-cc2, L1 + L2, f12);

    float s00  = fmaf(a00, a00, fmaf(a01, a01, a02 * a02));
    float s11  = fmaf(a01, a01, fmaf(a11, a11, a12 * a12));
    float s22  = fmaf(a02, a02, fmaf(a12, a12, a22 * a22));
    float s01  = fmaf(a01, a00 + a11, a02 * a12);
    float s02  = fmaf(a02, a00 + a22, a01 * a12);
    float s12m = fmaf(a12, a11 + a22, a01 * a02);

    y00 = fmaf(cc2, s00,  fmaf(k1, a00, k0));
    y11 = fmaf(cc2, s11,  fmaf(k1, a11, k0));
    y22 = fmaf(cc2, s22,  fmaf(k1, a22, k0));
    y01 = fmaf(cc2, s01,  k1 * a01);
    y02 = fmaf(cc2, s02,  k1 * a02);
    y12 = fmaf(cc2, s12m, k1 * a12);
}

// compute 4 voxels from 6 f32x4 plane-vectors, store 9 f32x4 planes at +off
__device__ __forceinline__ void stage(
    const f32x4 &A00, const f32x4 &A01, const f32x4 &A02,
    const f32x4 &A11, const f32x4 &A12, const f32x4 &A22,
    float* yb, int off)
{
    float O00[4], O01[4], O02[4], O11[4], O12[4], O22[4];
#pragma unroll
    for (int j = 0; j < 4; ++j)
        logm3(A00[j], A01[j], A02[j], A11[j], A12[j], A22[j],
              O00[j], O01[j], O02[j], O11[j], O12[j], O22[j]);

    f32x4 W;
#define STORE(ch, arr) \
    W[0] = arr[0]; W[1] = arr[1]; W[2] = arr[2]; W[3] = arr[3]; \
    *reinterpret_cast<f32x4*>(yb + (size_t)(ch) * NV + off) = W;
    STORE(0, O00) STORE(1, O01) STORE(2, O02)
    STORE(3, O01) STORE(4, O11) STORE(5, O12)
    STORE(6, O02) STORE(7, O12) STORE(8, O22)
#undef STORE
}

extern "C" __global__ void __launch_bounds__(256, 4)
logm_kernel(const float* __restrict__ x, float* __restrict__ y)
{
    int t = blockIdx.x * blockDim.x + threadIdx.x;     // < 262144
    int g = t << 3;                                    // first of 8 adjacent voxels
    int b = g >> 20;
    int v = g & (NV - 1);
    const float* xb = x + ((size_t)b * 9) * NV + v;
    float*       yb = y + ((size_t)b * 9) * NV + v;

    // all 12 loads up front (2 per plane, adjacent 16B): B stays in flight
    f32x4 A00 = *reinterpret_cast<const f32x4*>(xb + 0 * (size_t)NV);
    f32x4 A01 = *reinterpret_cast<const f32x4*>(xb + 1 * (size_t)NV);
    f32x4 A02 = *reinterpret_cast<const f32x4*>(xb + 2 * (size_t)NV);
    f32x4 A11 = *reinterpret_cast<const f32x4*>(xb + 4 * (size_t)NV);
    f32x4 A12 = *reinterpret_cast<const f32x4*>(xb + 5 * (size_t)NV);
    f32x4 A22 = *reinterpret_cast<const f32x4*>(xb + 8 * (size_t)NV);
    f32x4 B00 = *reinterpret_cast<const f32x4*>(xb + 0 * (size_t)NV + 4);
    f32x4 B01 = *reinterpret_cast<const f32x4*>(xb + 1 * (size_t)NV + 4);
    f32x4 B02 = *reinterpret_cast<const f32x4*>(xb + 2 * (size_t)NV + 4);
    f32x4 B11 = *reinterpret_cast<const f32x4*>(xb + 4 * (size_t)NV + 4);
    f32x4 B12 = *reinterpret_cast<const f32x4*>(xb + 5 * (size_t)NV + 4);
    f32x4 B22 = *reinterpret_cast<const f32x4*>(xb + 8 * (size_t)NV + 4);

    stage(A00, A01, A02, A11, A12, A22, yb, 0);  // B loads in flight here
    stage(B00, B01, B02, B11, B12, B22, yb, 4);  // A stores drain here
}

extern "C" void kernel_launch(void* const* d_in, const int* in_sizes, int n_in,
                              void* d_out, int out_size, void* d_ws, size_t ws_size,
                              hipStream_t stream) {
    const float* x = (const float*)d_in[0];
    float*       y = (float*)d_out;
    const int total_threads = BT * NV / 8;             // 262144
    dim3 grid(total_threads / 256), block(256);
    hipLaunchKernelGGL(logm_kernel, grid, block, 0, stream, x, y);
}

// Round 15
// 25.077 us; speedup vs baseline: 1.9378x; 1.9378x over previous
//
#include <hip/hip_runtime.h>

// Logm of 2*2^20 independent 3x3 SPD matrices — closed-form eigenvalues.
// Layout: x[b][c][v], c = 3*i+j, plane stride NV = 2^20 floats.
// Input bit-symmetric -> read only upper-triangle planes {0,1,2,4,5,8}.
// Burst-doubling test, COALESCED this time (r14 interleaved lanes' tiles ->
// 16B-holed wave stores -> 2x write amplification, WRITE_SIZE 144MB):
// each WAVE owns 512 contiguous voxels per plane; thread handles tile A at
// wave*512 + lane*4 and tile B at +256 floats. Every f32x4 store instruction
// is a contiguous 1KB wave burst; the wave touches 2KB sequential per plane.
// All 12 loads up front (B in flight under A's compute; A's stores drain
// under B's compute). Deg-3 A&S acos (err 7e-5 rad).
// Per voxel: char-poly -> Cardano trig eigenvalues -> Newton divided
// differences: log(M) = k0*I + k1*M + k2*M^2 (passed r8-r14).

#define NV (1 << 20)   // D*H*W
#define BT 2

typedef float f32x4 __attribute__((ext_vector_type(4)));

__device__ __forceinline__ float rcpf(float x) { return __builtin_amdgcn_rcpf(x); }

__device__ __forceinline__ void logm3(
    float a00, float a01, float a02, float a11, float a12, float a22,
    float &y00, float &y01, float &y02, float &y11, float &y12, float &y22)
{
    const float THIRD = 0.33333333333f;
    float m   = (a00 + a11 + a22) * THIRD;
    float b00 = a00 - m, b11 = a11 - m, b22 = a22 - m;
    float off2  = fmaf(a01, a01, fmaf(a02, a02, a12 * a12));
    float diag2 = fmaf(b00, b00, fmaf(b11, b11, b22 * b22));
    float p2 = fmaf(diag2, 1.0f / 6.0f, off2 * THIRD);   // p = tr(B^2)/6
    float sp = sqrtf(p2);
    float detB = b00 * fmaf(b11, b22, -a12 * a12)
               - a01 * fmaf(a01, b22, -a12 * a02)
               + a02 * fmaf(a01, a12, -b11 * a02);
    float q  = 0.5f * detB;
    float rr = q * rcpf(fmaxf(p2 * sp, 1e-30f));         // q / p^(3/2)
    rr = fminf(fmaxf(rr, -1.0f), 1.0f);

    // acos(rr): A&S 4.4.45 deg-3, |err| <= 6.8e-5 rad; reflect for rr<0
    float ar  = fabsf(rr);
    float acp = fmaf(ar, fmaf(ar, fmaf(ar,
        -0.0187293f, 0.0742610f), -0.2121144f), 1.5707288f);
    float A   = sqrtf(fmaxf(1.0f - ar, 0.0f)) * acp;
    float phi = (rr >= 0.0f) ? A : (3.14159265359f - A);
    float th  = phi * THIRD;                              // [0, pi/3]

    float c0  = __cosf(th);
    float s0  = sqrtf(fmaxf(fmaf(-c0, c0, 1.0f), 0.0f));
    float cm  = -0.5f * c0;
    float c1  = fmaf(-0.86602540378f, s0, cm);            // -> min
    float c2c = fmaf( 0.86602540378f, s0, cm);            // -> mid
    float tsp = 2.0f * sp;
    float L1 = fmaf(tsp, c0,  m);                         // max
    float L2 = fmaf(tsp, c2c, m);                         // mid
    float L3 = fmaf(tsp, c1,  m);                         // min

    float g1 = __logf(L1), g2 = __logf(L2), g3 = __logf(L3);

    float d12 = L1 - L2, d23 = L2 - L3;
    float d13 = fmaxf(L1 - L3, 1e-6f);
    float i2  = rcpf(L2), i3 = rcpf(L3);
    float x12 = d12 * i2, x23 = d23 * i3;
    float s12 = fmaf(x12, fmaf(x12, fmaf(x12, -0.25f, THIRD), -0.5f), 1.0f);
    float s23 = fmaf(x23, fmaf(x23, fmaf(x23, -0.25f, THIRD), -0.5f), 1.0f);
    float f12 = (x12 < 0.03f) ? s12 * i2 : (g1 - g2) * rcpf(fmaxf(d12, 1e-30f));
    float f23 = (x23 < 0.03f) ? s23 * i3 : (g2 - g3) * rcpf(fmaxf(d23, 1e-30f));
    float cc2 = (f12 - f23) * rcpf(d13);

    float k0 = fmaf(cc2, L1 * L2, fmaf(-f12, L1, g1));
    float k1 = fmaf(-cc2, L1 + L2, f12);

    float s00  = fmaf(a00, a00, fmaf(a01, a01, a02 * a02));
    float s11  = fmaf(a01, a01, fmaf(a11, a11, a12 * a12));
    float s22  = fmaf(a02, a02, fmaf(a12, a12, a22 * a22));
    float s01  = fmaf(a01, a00 + a11, a02 * a12);
    float s02  = fmaf(a02, a00 + a22, a01 * a12);
    float s12m = fmaf(a12, a11 + a22, a01 * a02);

    y00 = fmaf(cc2, s00,  fmaf(k1, a00, k0));
    y11 = fmaf(cc2, s11,  fmaf(k1, a11, k0));
    y22 = fmaf(cc2, s22,  fmaf(k1, a22, k0));
    y01 = fmaf(cc2, s01,  k1 * a01);
    y02 = fmaf(cc2, s02,  k1 * a02);
    y12 = fmaf(cc2, s12m, k1 * a12);
}

// compute 4 voxels from 6 f32x4 plane-vectors, store 9 f32x4 planes
__device__ __forceinline__ void stage(
    const f32x4 &A00, const f32x4 &A01, const f32x4 &A02,
    const f32x4 &A11, const f32x4 &A12, const f32x4 &A22, float* yb)
{
    float O00[4], O01[4], O02[4], O11[4], O12[4], O22[4];
#pragma unroll
    for (int j = 0; j < 4; ++j)
        logm3(A00[j], A01[j], A02[j], A11[j], A12[j], A22[j],
              O00[j], O01[j], O02[j], O11[j], O12[j], O22[j]);

    f32x4 W;
#define STORE(ch, arr) \
    W[0] = arr[0]; W[1] = arr[1]; W[2] = arr[2]; W[3] = arr[3]; \
    *reinterpret_cast<f32x4*>(yb + (size_t)(ch) * NV) = W;
    STORE(0, O00) STORE(1, O01) STORE(2, O02)
    STORE(3, O01) STORE(4, O11) STORE(5, O12)
    STORE(6, O02) STORE(7, O12) STORE(8, O22)
#undef STORE
}

extern "C" __global__ void __launch_bounds__(256, 4)
logm_kernel(const float* __restrict__ x, float* __restrict__ y)
{
    int t    = blockIdx.x * blockDim.x + threadIdx.x;  // < 262144
    int wave = t >> 6;
    int lane = t & 63;
    int g    = wave * 512 + lane * 4;                  // tile A: wave-contiguous 1KB
    int b    = g >> 20;
    int v    = g & (NV - 1);                           // tile B = v+256, same batch
    const float* xa = x + ((size_t)b * 9) * NV + v;
    float*       ya = y + ((size_t)b * 9) * NV + v;

    // all 12 loads up front: tile-B latency hides under tile-A compute
    f32x4 A00 = *reinterpret_cast<const f32x4*>(xa + 0 * (size_t)NV);
    f32x4 A01 = *reinterpret_cast<const f32x4*>(xa + 1 * (size_t)NV);
    f32x4 A02 = *reinterpret_cast<const f32x4*>(xa + 2 * (size_t)NV);
    f32x4 A11 = *reinterpret_cast<const f32x4*>(xa + 4 * (size_t)NV);
    f32x4 A12 = *reinterpret_cast<const f32x4*>(xa + 5 * (size_t)NV);
    f32x4 A22 = *reinterpret_cast<const f32x4*>(xa + 8 * (size_t)NV);
    f32x4 B00 = *reinterpret_cast<const f32x4*>(xa + 0 * (size_t)NV + 256);
    f32x4 B01 = *reinterpret_cast<const f32x4*>(xa + 1 * (size_t)NV + 256);
    f32x4 B02 = *reinterpret_cast<const f32x4*>(xa + 2 * (size_t)NV + 256);
    f32x4 B11 = *reinterpret_cast<const f32x4*>(xa + 4 * (size_t)NV + 256);
    f32x4 B12 = *reinterpret_cast<const f32x4*>(xa + 5 * (size_t)NV + 256);
    f32x4 B22 = *reinterpret_cast<const f32x4*>(xa + 8 * (size_t)NV + 256);

    stage(A00, A01, A02, A11, A12, A22, ya);        // B loads in flight here
    stage(B00, B01, B02, B11, B12, B22, ya + 256);  // A stores drain here
}

extern "C" void kernel_launch(void* const* d_in, const int* in_sizes, int n_in,
                              void* d_out, int out_size, void* d_ws, size_t ws_size,
                              hipStream_t stream) {
    const float* x = (const float*)d_in[0];
    float*       y = (float*)d_out;
    const int total_threads = BT * NV / 8;             // 262144
    dim3 grid(total_threads / 256), block(256);
    hipLaunchKernelGGL(logm_kernel, grid, block, 0, stream, x, y);
}